// Round 18
// baseline (312.541 us; speedup 1.0000x reference)
//
#include <hip/hip_runtime.h>
#include <cstdint>

#define N_NODES 50000
#define N_EDGES 500000
#define ET (N_NODES + N_EDGES)   /* 550000 edges incl. self-loops */
#define WSB 256                  /* k_wsum blocks */
#define EBLK 2149                /* ceil(ET/256) */
#define NEBLK 12500              /* ne elems 3.2M / 256 */

typedef unsigned short u16;
typedef unsigned int   u32;
typedef __attribute__((ext_vector_type(8))) short short8;   // 8 bf16 (4 VGPRs)
typedef __attribute__((ext_vector_type(4))) float f32x4;

__device__ __forceinline__ float bf2f(u16 s) { return __uint_as_float((u32)s << 16); }
__device__ __forceinline__ u16 f2bf(float f) {          // round-to-nearest-even
  u32 u = __float_as_uint(f);
  u32 r = (u + 0x7FFFu + ((u >> 16) & 1u)) >> 16;
  return (u16)r;
}
__device__ __forceinline__ void unpack8(uint4 u, float* f) {  // 8 bf16 -> fp32
  f[0] = __uint_as_float(u.x << 16); f[1] = __uint_as_float(u.x & 0xffff0000u);
  f[2] = __uint_as_float(u.y << 16); f[3] = __uint_as_float(u.y & 0xffff0000u);
  f[4] = __uint_as_float(u.z << 16); f[5] = __uint_as_float(u.z & 0xffff0000u);
  f[6] = __uint_as_float(u.w << 16); f[7] = __uint_as_float(u.w & 0xffff0000u);
}
__device__ __forceinline__ float lrelu(float v) { return v >= 0.f ? v : 0.2f * v; }

// per-wave inline dtype detection (deterministic: same 128 samples every wave)
__device__ __forceinline__ int detect_fp32(const u16* __restrict__ ne) {
  int lane = threadIdx.x & 63;
  int bad = 0;
  #pragma unroll
  for (int j = 0; j < 2; ++j) {
    float v = fabsf(bf2f(ne[lane * 2 + j * 128]));  // even positions only
    bad += (!(v < 16.0f)) ? 1 : 0;                  // catches NaN too
  }
  #pragma unroll
  for (int off = 32; off >= 1; off >>= 1) bad += __shfl_xor(bad, off, 64);
  return bad > 16;                                  // 1 => inputs are fp32
}

// ---------------- k_prep: degree + ne cvt + weight transposes + params ----
__global__ __launch_bounds__(256) void k_prep(const int* __restrict__ ei,
                                              int* __restrict__ deg,
                                              const void* __restrict__ ne_src,
                                              u16* __restrict__ ne_b,
                                              const void* __restrict__ w1src,
                                              u16* __restrict__ W1t,
                                              const void* __restrict__ w2src,
                                              u16* __restrict__ W2t,
                                              const void* s0, const void* s1,
                                              const void* s2, const void* s3,
                                              const void* s4, const void* s5,
                                              float* d0, float* d1, float* d2,
                                              float* d3, float* d4, float* d5) {
  int b = blockIdx.x, tid = threadIdx.x;
  if (b < EBLK) {                                    // degree histogram
    int e = b * 256 + tid;
    if (e < ET) {
      int d = (e < N_EDGES) ? ei[N_EDGES + e] : (e - N_EDGES);
      atomicAdd(&deg[d], 1);
    }
    return;
  }
  int fp32 = detect_fp32((const u16*)ne_src);
  b -= EBLK;
  if (b < NEBLK) {                                   // ne -> bf16
    int i = b * 256 + tid;
    ne_b[i] = fp32 ? f2bf(((const float*)ne_src)[i]) : ((const u16*)ne_src)[i];
    return;
  }
  b -= NEBLK;
  if (b < 640) {                                     // weight transposes
    int i = b * 256 + tid;
    if (i < 32768) {                                 // W1: K=64, N=512
      int n = i >> 6, k = i & 63;
      W1t[i] = fp32 ? f2bf(((const float*)w1src)[k * 512 + n])
                    : ((const u16*)w1src)[k * 512 + n];
    } else {                                         // W2: K=512, N=256
      int j = i - 32768;
      int n = j >> 9, k = j & 511;
      W2t[j] = fp32 ? f2bf(((const float*)w2src)[k * 256 + n])
                    : ((const u16*)w2src)[k * 256 + n];
    }
    return;
  }
  b -= 640;
  {                                                  // small param vectors
    int i = b * 256 + tid;
    const void* s; float* d; int j;
    if      (i < 512)  { s = s0; d = d0; j = i; }
    else if (i < 1024) { s = s1; d = d1; j = i - 512; }
    else if (i < 1536) { s = s2; d = d2; j = i - 1024; }
    else if (i < 1792) { s = s3; d = d3; j = i - 1536; }
    else if (i < 2048) { s = s4; d = d4; j = i - 1792; }
    else if (i < 2304) { s = s5; d = d5; j = i - 2048; }
    else return;
    d[j] = fp32 ? ((const float*)s)[j] : bf2f(((const u16*)s)[j]);
  }
}

// ---------------- va vectors, both layers ----------------
__global__ void k_vab(const u16* __restrict__ W1t,
                      const float* __restrict__ as1v, const float* __restrict__ ad1v,
                      float* __restrict__ va_s, float* __restrict__ va_d,
                      const u16* __restrict__ W2t,
                      const float* __restrict__ as2v, const float* __restrict__ ad2v,
                      float* __restrict__ va2_s, float* __restrict__ va2_d) {
  if (blockIdx.x == 0) {
    int t = threadIdx.x;           // h = t>>6, k = t&63
    int h = t >> 6, k = t & 63;
    float s = 0.f, d = 0.f;
    for (int c = 0; c < 128; ++c) {
      float w = bf2f(W1t[(size_t)(h * 128 + c) * 64 + k]);
      s = fmaf(as1v[h * 128 + c], w, s);
      d = fmaf(ad1v[h * 128 + c], w, d);
    }
    va_s[t] = s;
    va_d[t] = d;
  } else {
    int k = (blockIdx.x - 1) * 256 + threadIdx.x;
    if (k >= 512) return;
    float s = 0.f, d = 0.f;
    for (int c = 0; c < 256; ++c) {
      float w = bf2f(W2t[(size_t)c * 512 + k]);
      s = fmaf(as2v[c], w, s);
      d = fmaf(ad2v[c], w, d);
    }
    va2_s[k] = s;
    va2_d[k] = d;
  }
}

// ---------------- CSR scan ----------------
__global__ __launch_bounds__(1024) void k_partial(const int* __restrict__ deg,
                                                  int* __restrict__ excl,
                                                  int* __restrict__ btot) {
  __shared__ int wsum[16];
  int tid = threadIdx.x;
  int i = blockIdx.x * 1024 + tid;
  int v = (i < N_NODES) ? deg[i] : 0;
  int lane = tid & 63, wid = tid >> 6;
  int incl = v;
  #pragma unroll
  for (int off = 1; off < 64; off <<= 1) {
    int t = __shfl_up(incl, off, 64);
    if (lane >= off) incl += t;
  }
  if (lane == 63) wsum[wid] = incl;
  __syncthreads();
  int prefix = 0;
  for (int w = 0; w < wid; ++w) prefix += wsum[w];
  if (i < N_NODES) excl[i] = prefix + incl - v;
  if (tid == 1023) btot[blockIdx.x] = prefix + incl;
}

__global__ void k_bases(const int* __restrict__ btot, int* __restrict__ bbase,
                        int* __restrict__ row_off, int nb) {
  int lane = threadIdx.x;  // 64 threads, single wave
  int v = (lane < nb) ? btot[lane] : 0;
  int incl = v;
  #pragma unroll
  for (int off = 1; off < 64; off <<= 1) {
    int t = __shfl_up(incl, off, 64);
    if (lane >= off) incl += t;
  }
  if (lane < nb) bbase[lane] = incl - v;
  if (lane == 0) row_off[N_NODES] = ET;
}

__global__ __launch_bounds__(1024) void k_add(int* __restrict__ row_off,
                                              int* __restrict__ cursor,
                                              const int* __restrict__ bbase) {
  int i = blockIdx.x * 1024 + threadIdx.x;
  if (i < N_NODES) {
    int r = row_off[i] + bbase[blockIdx.x];
    row_off[i] = r;
    cursor[i] = r;
  }
}

// ---------------- k_scal: scatter (u16 srcs) + alpha1 (16-wide reductions) ----
__global__ __launch_bounds__(256) void k_scal(const int* __restrict__ ei,
                                              int* __restrict__ cursor,
                                              u16* __restrict__ srcs,
                                              const u16* __restrict__ ne_b,
                                              const float* __restrict__ va_s,
                                              const float* __restrict__ va_d,
                                              float* __restrict__ as_o,
                                              float* __restrict__ ad_o) {
  int b = blockIdx.x;
  if (b < EBLK) {                                    // scatter
    int e = b * 256 + threadIdx.x;
    if (e >= ET) return;
    int s, d;
    if (e < N_EDGES) { s = ei[e]; d = ei[N_EDGES + e]; }
    else { s = d = e - N_EDGES; }
    int pos = atomicAdd(&cursor[d], 1);
    srcs[pos] = (u16)s;                              // node ids < 65536
    return;
  }
  b -= EBLK;                                         // alpha1: wave per node
  int wid = threadIdx.x >> 6, lane = threadIdx.x & 63;
  int n = b * 4 + wid;
  if (n >= N_NODES) return;
  int h = lane >> 4, il = lane & 15;                 // head, lane-in-group
  u32 u2[2];
  *(uint2*)u2 = *(const uint2*)(ne_b + (size_t)n * 64 + il * 4);
  float f[4];
  f[0] = bf2f((u16)u2[0]); f[1] = bf2f((u16)(u2[0] >> 16));
  f[2] = bf2f((u16)u2[1]); f[3] = bf2f((u16)(u2[1] >> 16));
  float4 vs = *(const float4*)(va_s + h * 64 + il * 4);
  float4 vd = *(const float4*)(va_d + h * 64 + il * 4);
  float s = f[0] * vs.x + f[1] * vs.y + f[2] * vs.z + f[3] * vs.w;
  float d = f[0] * vd.x + f[1] * vd.y + f[2] * vd.z + f[3] * vd.w;
  #pragma unroll
  for (int off = 8; off >= 1; off >>= 1) {           // 16-wide reductions
    s += __shfl_xor(s, off, 64);
    d += __shfl_xor(d, off, 64);
  }
  if (il == 0) { as_o[n * 4 + h] = s; ad_o[n * 4 + h] = d; }
}

// ---------------- layer-1 GEMM + bias + ELU + alpha2, LDS-staged epilogue ----
#define LSTR 40
#define CPAD 136   /* C-tile row stride in u16: 272B, 16B-aligned, conflict-light */
__global__ __launch_bounds__(256) void k_gemm_l1(const u16* __restrict__ aggne,
                                                 const u16* __restrict__ W1t,
                                                 const float* __restrict__ b1f,
                                                 const float* __restrict__ va2_s,
                                                 const float* __restrict__ va2_d,
                                                 u16* __restrict__ x2,
                                                 float* __restrict__ as2,
                                                 float* __restrict__ ad2, int M) {
  __shared__ __align__(16) u16 smem[128 * CPAD];   // 34.8 KB; aliases As/Bs/Cs
  u16* As = smem;                                  // 128*LSTR = 5120
  u16* Bs = smem + 128 * LSTR;                     // 5120
  const int tid = threadIdx.x;
  const int lane = tid & 63, wid = tid >> 6;
  const int wr = (wid >> 1) * 64, wc = (wid & 1) * 64;
  const int m = lane & 15, q = lane >> 4;
  const int row0 = blockIdx.x * 128, head = blockIdx.y;
  const u16* Bt = W1t + (size_t)head * 128 * 64;   // [128 rows][64]
  f32x4 acc[4][4] = {};
  #pragma unroll
  for (int kk = 0; kk < 64; kk += 32) {
    #pragma unroll
    for (int i = 0; i < 2; ++i) {             // stage A 128x32 (lda=256)
      int v = tid + i * 256;
      int row = v >> 2, ch = (v & 3) * 8;
      uint4 u = make_uint4(0, 0, 0, 0);
      int gr = row0 + row;
      if (gr < M) u = *(const uint4*)(aggne + (size_t)gr * 256 + head * 64 + kk + ch);
      *(uint4*)(As + row * LSTR + ch) = u;
    }
    #pragma unroll
    for (int i = 0; i < 2; ++i) {             // stage Bt 128x32 (stride 64)
      int v = tid + i * 256;
      int row = v >> 2, ch = (v & 3) * 8;
      uint4 u = *(const uint4*)(Bt + (size_t)row * 64 + kk + ch);
      *(uint4*)(Bs + row * LSTR + ch) = u;
    }
    __syncthreads();
    short8 af[4], bfr[4];
    #pragma unroll
    for (int t = 0; t < 4; ++t) {
      af[t]  = *(const short8*)(As + (wr + t * 16 + m) * LSTR + q * 8);
      bfr[t] = *(const short8*)(Bs + (wc + t * 16 + m) * LSTR + q * 8);
    }
    #pragma unroll
    for (int mt = 0; mt < 4; ++mt)
      #pragma unroll
      for (int nt = 0; nt < 4; ++nt)
        acc[mt][nt] = __builtin_amdgcn_mfma_f32_16x16x32_bf16(
            af[mt], bfr[nt], acc[mt][nt], 0, 0, 0);
    __syncthreads();
  }
  // bias + ELU, stage bf16 C-tile in LDS (safe: As/Bs dead after final barrier)
  u16* Cs = smem;
  #pragma unroll
  for (int mt = 0; mt < 4; ++mt) {
    #pragma unroll
    for (int nt = 0; nt < 4; ++nt) {
      int lc = wc + nt * 16 + m;              // local col in [0,128)
      float bias = b1f[head * 128 + lc];
      #pragma unroll
      for (int r = 0; r < 4; ++r) {
        float v = acc[mt][nt][r] + bias;
        v = v > 0.f ? v : (__expf(v) - 1.0f);   // ELU
        Cs[(wr + mt * 16 + q * 4 + r) * CPAD + lc] = f2bf(v);
      }
    }
  }
  __syncthreads();
  // coalesced x2 write (uint4) + alpha2 dot from staged rows
  int row = tid >> 1, half = tid & 1;         // 2 threads per row, 64 u16 each
  int gr = row0 + row;
  if (gr < M) {
    const u16* src = Cs + row * CPAD + half * 64;
    int cb = head * 128 + half * 64;
    float s = 0.f, d = 0.f;
    #pragma unroll
    for (int i = 0; i < 8; ++i) {
      uint4 u = *(const uint4*)(src + i * 8);
      *(uint4*)(x2 + (size_t)gr * 512 + cb + i * 8) = u;
      float f[8];
      unpack8(u, f);
      const float* pvs = va2_s + cb + i * 8;
      const float* pvd = va2_d + cb + i * 8;
      #pragma unroll
      for (int j = 0; j < 8; ++j) {
        s = fmaf(f[j], pvs[j], s);
        d = fmaf(f[j], pvd[j], d);
      }
    }
    s += __shfl_xor(s, 1, 64);                // partner = other half, same row
    d += __shfl_xor(d, 1, 64);
    if (half == 0) {
      atomicAdd(&as2[gr], s);
      atomicAdd(&ad2[gr], d);
    }
  }
}

// ---------------- fused layer-1 aggregation (u16 srcs, 8-deep gather) ----
// NO max pass; stats pass with 2 interleaved partial sums; gather 8 rows
// in flight, then 4, then scalar remainder.
__global__ __launch_bounds__(256) void k_fagg1(const int* __restrict__ row_off,
                                               const u16* __restrict__ srcs,
                                               const u16* __restrict__ ne_b,
                                               const float* __restrict__ as1,
                                               const float* __restrict__ ad1,
                                               u16* __restrict__ aggne) {
  int wid = threadIdx.x >> 6, lane = threadIdx.x & 63;
  int n = blockIdx.x * 4 + wid;
  if (n >= N_NODES) return;
  int start = row_off[n], end = row_off[n + 1];
  int g = lane >> 4, il = lane & 15;     // head group g, lane-in-group
  float adn_g = ad1[n * 4 + g];
  float sum0 = 0.f, sum1 = 0.f;          // 2 partial sums: 2 gathers in flight
  for (int e0 = start; e0 < end; e0 += 32) {
    int e = e0 + il, e2 = e0 + 16 + il;
    if (e < end)  sum0 += __expf(lrelu(as1[(int)srcs[e] * 4 + g] + adn_g));
    if (e2 < end) sum1 += __expf(lrelu(as1[(int)srcs[e2] * 4 + g] + adn_g));
  }
  float sum = sum0 + sum1;
  #pragma unroll
  for (int off = 8; off >= 1; off >>= 1) sum += __shfl_xor(sum, off, 64);
  float inv = 1.0f / (sum + 1e-16f);
  float i_[4], d_[4];
  #pragma unroll
  for (int h = 0; h < 4; ++h) {
    i_[h] = __shfl(inv, h * 16, 64);
    d_[h] = __shfl(adn_g, h * 16, 64);
  }
  float acc[4] = {};
  for (int e0 = start; e0 < end; e0 += 64) {
    int lim = end - e0; if (lim > 64) lim = 64;
    int es = e0 + lane;
    int sreg = (int)srcs[es < end ? es : end - 1];
    float4 a = *(const float4*)(as1 + sreg * 4);
    float wreg[4];
    wreg[0] = __expf(lrelu(a.x + d_[0])) * i_[0];
    wreg[1] = __expf(lrelu(a.y + d_[1])) * i_[1];
    wreg[2] = __expf(lrelu(a.z + d_[2])) * i_[2];
    wreg[3] = __expf(lrelu(a.w + d_[3])) * i_[3];
    int j = 0;
    for (; j + 7 < lim; j += 8) {           // 8 rows in flight
      int s0 = __shfl(sreg, j, 64),     s1 = __shfl(sreg, j + 1, 64);
      int s2 = __shfl(sreg, j + 2, 64), s3 = __shfl(sreg, j + 3, 64);
      int s4 = __shfl(sreg, j + 4, 64), s5 = __shfl(sreg, j + 5, 64);
      int s6 = __shfl(sreg, j + 6, 64), s7 = __shfl(sreg, j + 7, 64);
      float f0 = bf2f(ne_b[(size_t)s0 * 64 + lane]);
      float f1 = bf2f(ne_b[(size_t)s1 * 64 + lane]);
      float f2 = bf2f(ne_b[(size_t)s2 * 64 + lane]);
      float f3 = bf2f(ne_b[(size_t)s3 * 64 + lane]);
      float f4 = bf2f(ne_b[(size_t)s4 * 64 + lane]);
      float f5 = bf2f(ne_b[(size_t)s5 * 64 + lane]);
      float f6 = bf2f(ne_b[(size_t)s6 * 64 + lane]);
      float f7 = bf2f(ne_b[(size_t)s7 * 64 + lane]);
      #pragma unroll
      for (int h = 0; h < 4; ++h) {
        acc[h] = fmaf(__shfl(wreg[h], j, 64), f0, acc[h]);
        acc[h] = fmaf(__shfl(wreg[h], j + 1, 64), f1, acc[h]);
        acc[h] = fmaf(__shfl(wreg[h], j + 2, 64), f2, acc[h]);
        acc[h] = fmaf(__shfl(wreg[h], j + 3, 64), f3, acc[h]);
        acc[h] = fmaf(__shfl(wreg[h], j + 4, 64), f4, acc[h]);
        acc[h] = fmaf(__shfl(wreg[h], j + 5, 64), f5, acc[h]);
        acc[h] = fmaf(__shfl(wreg[h], j + 6, 64), f6, acc[h]);
        acc[h] = fmaf(__shfl(wreg[h], j + 7, 64), f7, acc[h]);
      }
    }
    for (; j + 3 < lim; j += 4) {           // 4 rows in flight
      int s0 = __shfl(sreg, j, 64),     s1 = __shfl(sreg, j + 1, 64);
      int s2 = __shfl(sreg, j + 2, 64), s3 = __shfl(sreg, j + 3, 64);
      float f0 = bf2f(ne_b[(size_t)s0 * 64 + lane]);
      float f1 = bf2f(ne_b[(size_t)s1 * 64 + lane]);
      float f2 = bf2f(ne_b[(size_t)s2 * 64 + lane]);
      float f3 = bf2f(ne_b[(size_t)s3 * 64 + lane]);
      #pragma unroll
      for (int h = 0; h < 4; ++h) {
        acc[h] = fmaf(__shfl(wreg[h], j, 64), f0, acc[h]);
        acc[h] = fmaf(__shfl(wreg[h], j + 1, 64), f1, acc[h]);
        acc[h] = fmaf(__shfl(wreg[h], j + 2, 64), f2, acc[h]);
        acc[h] = fmaf(__shfl(wreg[h], j + 3, 64), f3, acc[h]);
      }
    }
    for (; j < lim; ++j) {
      int s0 = __shfl(sreg, j, 64);
      float f0 = bf2f(ne_b[(size_t)s0 * 64 + lane]);
      #pragma unroll
      for (int h = 0; h < 4; ++h)
        acc[h] = fmaf(__shfl(wreg[h], j, 64), f0, acc[h]);
    }
  }
  #pragma unroll
  for (int h = 0; h < 4; ++h)
    aggne[(size_t)n * 256 + h * 64 + lane] = f2bf(acc[h]);
}

// ---------------- layer-2: per-src total softmax weight c[s], no max pass ----
__global__ __launch_bounds__(256) void k_nodew(const int* __restrict__ row_off,
                                               const u16* __restrict__ srcs,
                                               const float* __restrict__ as2,
                                               const float* __restrict__ ad2,
                                               float* __restrict__ c) {
  int wid = threadIdx.x >> 6, lane = threadIdx.x & 63;
  int n = blockIdx.x * 4 + wid;
  if (n >= N_NODES) return;
  int start = row_off[n], end = row_off[n + 1];
  int deg = end - start;
  float adn = ad2[n];
  if (deg <= 64) {
    int e = start + (lane < deg ? lane : 0);
    int s = (int)srcs[e];
    float ex = (lane < deg) ? __expf(lrelu(as2[s] + adn)) : 0.f;
    float sum = ex;
    #pragma unroll
    for (int off = 32; off >= 1; off >>= 1) sum += __shfl_xor(sum, off, 64);
    float w = ex / (sum + 1e-16f);
    if (lane < deg) atomicAdd(&c[s], w);
  } else {
    float sum = 0.f;
    for (int e = start + lane; e < end; e += 64)
      sum += __expf(lrelu(as2[(int)srcs[e]] + adn));
    #pragma unroll
    for (int off = 32; off >= 1; off >>= 1) sum += __shfl_xor(sum, off, 64);
    float inv = 1.0f / (sum + 1e-16f);
    for (int e = start + lane; e < end; e += 64) {
      int s = (int)srcs[e];
      float w = __expf(lrelu(as2[s] + adn)) * inv;
      atomicAdd(&c[s], w);
    }
  }
}

// ---------------- weighted column sum: s_vec[ch] = sum_n c[n]*x2[n][ch] ----
__global__ __launch_bounds__(256) void k_wsum(const u16* __restrict__ x2,
                                              const float* __restrict__ c,
                                              float* __restrict__ s_vec) {
  __shared__ float part[4][512];
  int wid = threadIdx.x >> 6, lane = threadIdx.x & 63;
  int wglob = blockIdx.x * 4 + wid;
  float acc[8] = {};
  int n = wglob;
  for (; n + WSB * 4 < N_NODES; n += WSB * 8) {   // two rows in flight
    int n2 = n + WSB * 4;
    float c0 = c[n], c1 = c[n2];
    uint4 u0 = *(const uint4*)(x2 + (size_t)n * 512 + lane * 8);
    uint4 u1 = *(const uint4*)(x2 + (size_t)n2 * 512 + lane * 8);
    float f0[8], f1[8];
    unpack8(u0, f0); unpack8(u1, f1);
    #pragma unroll
    for (int j = 0; j < 8; ++j) {
      acc[j] = fmaf(c0, f0[j], acc[j]);
      acc[j] = fmaf(c1, f1[j], acc[j]);
    }
  }
  if (n < N_NODES) {
    float c0 = c[n];
    uint4 u0 = *(const uint4*)(x2 + (size_t)n * 512 + lane * 8);
    float f0[8];
    unpack8(u0, f0);
    #pragma unroll
    for (int j = 0; j < 8; ++j) acc[j] = fmaf(c0, f0[j], acc[j]);
  }
  #pragma unroll
  for (int j = 0; j < 8; ++j) part[wid][lane * 8 + j] = acc[j];
  __syncthreads();
  int t = threadIdx.x;
  float v0 = part[0][t] + part[1][t] + part[2][t] + part[3][t];
  float v1 = part[0][t + 256] + part[1][t + 256] + part[2][t + 256] + part[3][t + 256];
  atomicAdd(&s_vec[t], v0);
  atomicAdd(&s_vec[t + 256], v1);
}

// ---------------- tiny GEMM + final output (merged) ----------------
__global__ __launch_bounds__(256) void k_tinyfinal(const float* __restrict__ s_vec,
                                                   const u16* __restrict__ W2t,
                                                   const float* __restrict__ b2f,
                                                   float* __restrict__ out,
                                                   int out_size) {
  int wid = threadIdx.x >> 6, lane = threadIdx.x & 63;
  int cbase = blockIdx.x * 64 + wid * 16;
  float sv[8];
  #pragma unroll
  for (int j = 0; j < 8; ++j) sv[j] = s_vec[lane * 8 + j];
  for (int i = 0; i < 16; ++i) {
    int cc = cbase + i;
    uint4 u = *(const uint4*)(W2t + (size_t)cc * 512 + lane * 8);
    float f[8];
    unpack8(u, f);
    float p = 0.f;
    #pragma unroll
    for (int j = 0; j < 8; ++j) p = fmaf(sv[j], f[j], p);
    #pragma unroll
    for (int off = 32; off >= 1; off >>= 1) p += __shfl_xor(p, off, 64);
    if (lane == 0) {
      float val = p * (1.0f / (float)N_NODES) + b2f[cc];
      for (int o = cc; o < out_size; o += 256) out[o] = val;
    }
  }
}

// ---------------- launch ----------------
extern "C" void kernel_launch(void* const* d_in, const int* in_sizes, int n_in,
                              void* d_out, int out_size, void* d_ws, size_t ws_size,
                              hipStream_t stream) {
  (void)in_sizes; (void)n_in; (void)ws_size;
  const int* edge_index = (const int*)d_in[0];
  float* out = (float*)d_out;   // reference output dtype is float32

  char* w = (char*)d_ws;
  size_t off = 0;
  auto alloc = [&](size_t bytes) -> void* {
    void* p = w + off;
    off += (bytes + 255) & ~(size_t)255;
    return p;
  };
  u16*   ne_b    = (u16*)  alloc((size_t)N_NODES * 64 * 2);   // 6.4 MB bf16
  u16*   W1t     = (u16*)  alloc(32768 * 2);                  // [512][64]
  u16*   W2t     = (u16*)  alloc(131072 * 2);                 // [256][512]
  float* as1v    = (float*)alloc(512 * 4);
  float* ad1v    = (float*)alloc(512 * 4);
  float* b1f     = (float*)alloc(512 * 4);
  float* as2v    = (float*)alloc(256 * 4);
  float* ad2v    = (float*)alloc(256 * 4);
  float* b2f     = (float*)alloc(256 * 4);
  float* va_s    = (float*)alloc(256 * 4);
  float* va_d    = (float*)alloc(256 * 4);
  float* va2_s   = (float*)alloc(512 * 4);
  float* va2_d   = (float*)alloc(512 * 4);
  u16*   aggne   = (u16*)  alloc((size_t)N_NODES * 256 * 2);  // 25.6 MB
  u16*   x2      = (u16*)  alloc((size_t)N_NODES * 512 * 2);  // 51.2 MB
  float* as1     = (float*)alloc((size_t)N_NODES * 4 * 4);
  float* ad1     = (float*)alloc((size_t)N_NODES * 4 * 4);
  // ---- zeroed-every-call region (contiguous, one memset) ----
  size_t z0 = off;
  float* as2     = (float*)alloc((size_t)N_NODES * 4);
  float* ad2     = (float*)alloc((size_t)N_NODES * 4);
  float* cwt     = (float*)alloc((size_t)N_NODES * 4);
  float* s_vec   = (float*)alloc(512 * 4);
  int*   deg     = (int*)  alloc((size_t)N_NODES * 4);
  size_t z1 = off;
  // -----------------------------------------------------------
  int*   row_off = (int*)  alloc((size_t)(N_NODES + 1) * 4);
  int*   cursor  = (int*)  alloc((size_t)N_NODES * 4);
  u16*   srcs    = (u16*)  alloc((size_t)ET * 2);             // node ids fit u16
  int*   btot    = (int*)  alloc(64 * 4);
  int*   bbase   = (int*)  alloc(64 * 4);

  hipMemsetAsync(w + z0, 0, z1 - z0, stream);

  // prep: degree + ne cvt + weight transposes + params (inline dtype detect)
  k_prep<<<EBLK + NEBLK + 640 + 9, 256, 0, stream>>>(
      edge_index, deg, d_in[2], ne_b, d_in[3], W1t, d_in[7], W2t,
      d_in[4], d_in[5], d_in[6], d_in[8], d_in[9], d_in[10],
      as1v, ad1v, b1f, as2v, ad2v, b2f);
  k_vab<<<3, 256, 0, stream>>>(W1t, as1v, ad1v, va_s, va_d,
                               W2t, as2v, ad2v, va2_s, va2_d);

  // CSR scan
  k_partial<<<49, 1024, 0, stream>>>(deg, row_off, btot);
  k_bases  <<<1, 64, 0, stream>>>(btot, bbase, row_off, 49);
  k_add    <<<49, 1024, 0, stream>>>(row_off, cursor, bbase);

  // scatter (u16 srcs) + alpha1 (merged, 16-wide reductions)
  k_scal<<<EBLK + (N_NODES + 3) / 4, 256, 0, stream>>>(
      edge_index, cursor, srcs, ne_b, va_s, va_d, as1, ad1);

  // layer 1: fused agg over ne (8-deep gather), GEMM(+bias+ELU+alpha2) -> x2
  k_fagg1<<<(N_NODES + 3) / 4, 256, 0, stream>>>(row_off, srcs, ne_b, as1, ad1, aggne);
  dim3 gl1((N_NODES + 127) / 128, 4);
  k_gemm_l1<<<gl1, 256, 0, stream>>>(aggne, W1t, b1f, va2_s, va2_d, x2, as2, ad2,
                                     N_NODES);

  // layer 2 (mean-reassociated)
  k_nodew<<<(N_NODES + 3) / 4, 256, 0, stream>>>(row_off, srcs, as2, ad2, cwt);
  k_wsum<<<WSB, 256, 0, stream>>>(x2, cwt, s_vec);
  k_tinyfinal<<<4, 256, 0, stream>>>(s_vec, W2t, b2f, out, out_size);
}

// Round 19
// 306.299 us; speedup vs baseline: 1.0204x; 1.0204x over previous
//
#include <hip/hip_runtime.h>
#include <cstdint>

#define N_NODES 50000
#define N_EDGES 500000
#define ET (N_NODES + N_EDGES)   /* 550000 edges incl. self-loops */
#define WSB 256                  /* k_wsum blocks */
#define EBLK 2149                /* ceil(ET/256) */
#define NEBLK 12500              /* ne elems 3.2M / 256 */

typedef unsigned short u16;
typedef unsigned int   u32;
typedef __attribute__((ext_vector_type(8))) short short8;   // 8 bf16 (4 VGPRs)
typedef __attribute__((ext_vector_type(4))) float f32x4;

__device__ __forceinline__ float bf2f(u16 s) { return __uint_as_float((u32)s << 16); }
__device__ __forceinline__ u16 f2bf(float f) {          // round-to-nearest-even
  u32 u = __float_as_uint(f);
  u32 r = (u + 0x7FFFu + ((u >> 16) & 1u)) >> 16;
  return (u16)r;
}
__device__ __forceinline__ void unpack8(uint4 u, float* f) {  // 8 bf16 -> fp32
  f[0] = __uint_as_float(u.x << 16); f[1] = __uint_as_float(u.x & 0xffff0000u);
  f[2] = __uint_as_float(u.y << 16); f[3] = __uint_as_float(u.y & 0xffff0000u);
  f[4] = __uint_as_float(u.z << 16); f[5] = __uint_as_float(u.z & 0xffff0000u);
  f[6] = __uint_as_float(u.w << 16); f[7] = __uint_as_float(u.w & 0xffff0000u);
}
__device__ __forceinline__ float lrelu(float v) { return v >= 0.f ? v : 0.2f * v; }

// per-wave inline dtype detection (deterministic: same 128 samples every wave)
__device__ __forceinline__ int detect_fp32(const u16* __restrict__ ne) {
  int lane = threadIdx.x & 63;
  int bad = 0;
  #pragma unroll
  for (int j = 0; j < 2; ++j) {
    float v = fabsf(bf2f(ne[lane * 2 + j * 128]));  // even positions only
    bad += (!(v < 16.0f)) ? 1 : 0;                  // catches NaN too
  }
  #pragma unroll
  for (int off = 32; off >= 1; off >>= 1) bad += __shfl_xor(bad, off, 64);
  return bad > 16;                                  // 1 => inputs are fp32
}

// ---------------- k_prep: degree + ne cvt + weight transposes + params ----
__global__ __launch_bounds__(256) void k_prep(const int* __restrict__ ei,
                                              int* __restrict__ deg,
                                              const void* __restrict__ ne_src,
                                              u16* __restrict__ ne_b,
                                              const void* __restrict__ w1src,
                                              u16* __restrict__ W1t,
                                              const void* __restrict__ w2src,
                                              u16* __restrict__ W2t,
                                              const void* s0, const void* s1,
                                              const void* s2, const void* s3,
                                              const void* s4, const void* s5,
                                              float* d0, float* d1, float* d2,
                                              float* d3, float* d4, float* d5) {
  int b = blockIdx.x, tid = threadIdx.x;
  if (b < EBLK) {                                    // degree histogram
    int e = b * 256 + tid;
    if (e < ET) {
      int d = (e < N_EDGES) ? ei[N_EDGES + e] : (e - N_EDGES);
      atomicAdd(&deg[d], 1);
    }
    return;
  }
  int fp32 = detect_fp32((const u16*)ne_src);
  b -= EBLK;
  if (b < NEBLK) {                                   // ne -> bf16
    int i = b * 256 + tid;
    ne_b[i] = fp32 ? f2bf(((const float*)ne_src)[i]) : ((const u16*)ne_src)[i];
    return;
  }
  b -= NEBLK;
  if (b < 640) {                                     // weight transposes
    int i = b * 256 + tid;
    if (i < 32768) {                                 // W1: K=64, N=512
      int n = i >> 6, k = i & 63;
      W1t[i] = fp32 ? f2bf(((const float*)w1src)[k * 512 + n])
                    : ((const u16*)w1src)[k * 512 + n];
    } else {                                         // W2: K=512, N=256
      int j = i - 32768;
      int n = j >> 9, k = j & 511;
      W2t[j] = fp32 ? f2bf(((const float*)w2src)[k * 256 + n])
                    : ((const u16*)w2src)[k * 256 + n];
    }
    return;
  }
  b -= 640;
  {                                                  // small param vectors
    int i = b * 256 + tid;
    const void* s; float* d; int j;
    if      (i < 512)  { s = s0; d = d0; j = i; }
    else if (i < 1024) { s = s1; d = d1; j = i - 512; }
    else if (i < 1536) { s = s2; d = d2; j = i - 1024; }
    else if (i < 1792) { s = s3; d = d3; j = i - 1536; }
    else if (i < 2048) { s = s4; d = d4; j = i - 1792; }
    else if (i < 2304) { s = s5; d = d5; j = i - 2048; }
    else return;
    d[j] = fp32 ? ((const float*)s)[j] : bf2f(((const u16*)s)[j]);
  }
}

// ---------------- va vectors, both layers ----------------
__global__ void k_vab(const u16* __restrict__ W1t,
                      const float* __restrict__ as1v, const float* __restrict__ ad1v,
                      float* __restrict__ va_s, float* __restrict__ va_d,
                      const u16* __restrict__ W2t,
                      const float* __restrict__ as2v, const float* __restrict__ ad2v,
                      float* __restrict__ va2_s, float* __restrict__ va2_d) {
  if (blockIdx.x == 0) {
    int t = threadIdx.x;           // h = t>>6, k = t&63
    int h = t >> 6, k = t & 63;
    float s = 0.f, d = 0.f;
    for (int c = 0; c < 128; ++c) {
      float w = bf2f(W1t[(size_t)(h * 128 + c) * 64 + k]);
      s = fmaf(as1v[h * 128 + c], w, s);
      d = fmaf(ad1v[h * 128 + c], w, d);
    }
    va_s[t] = s;
    va_d[t] = d;
  } else {
    int k = (blockIdx.x - 1) * 256 + threadIdx.x;
    if (k >= 512) return;
    float s = 0.f, d = 0.f;
    for (int c = 0; c < 256; ++c) {
      float w = bf2f(W2t[(size_t)c * 512 + k]);
      s = fmaf(as2v[c], w, s);
      d = fmaf(ad2v[c], w, d);
    }
    va2_s[k] = s;
    va2_d[k] = d;
  }
}

// ---------------- CSR scan ----------------
__global__ __launch_bounds__(1024) void k_partial(const int* __restrict__ deg,
                                                  int* __restrict__ excl,
                                                  int* __restrict__ btot) {
  __shared__ int wsum[16];
  int tid = threadIdx.x;
  int i = blockIdx.x * 1024 + tid;
  int v = (i < N_NODES) ? deg[i] : 0;
  int lane = tid & 63, wid = tid >> 6;
  int incl = v;
  #pragma unroll
  for (int off = 1; off < 64; off <<= 1) {
    int t = __shfl_up(incl, off, 64);
    if (lane >= off) incl += t;
  }
  if (lane == 63) wsum[wid] = incl;
  __syncthreads();
  int prefix = 0;
  for (int w = 0; w < wid; ++w) prefix += wsum[w];
  if (i < N_NODES) excl[i] = prefix + incl - v;
  if (tid == 1023) btot[blockIdx.x] = prefix + incl;
}

__global__ void k_bases(const int* __restrict__ btot, int* __restrict__ bbase,
                        int* __restrict__ row_off, int nb) {
  int lane = threadIdx.x;  // 64 threads, single wave
  int v = (lane < nb) ? btot[lane] : 0;
  int incl = v;
  #pragma unroll
  for (int off = 1; off < 64; off <<= 1) {
    int t = __shfl_up(incl, off, 64);
    if (lane >= off) incl += t;
  }
  if (lane < nb) bbase[lane] = incl - v;
  if (lane == 0) row_off[N_NODES] = ET;
}

__global__ __launch_bounds__(1024) void k_add(int* __restrict__ row_off,
                                              int* __restrict__ cursor,
                                              const int* __restrict__ bbase) {
  int i = blockIdx.x * 1024 + threadIdx.x;
  if (i < N_NODES) {
    int r = row_off[i] + bbase[blockIdx.x];
    row_off[i] = r;
    cursor[i] = r;
  }
}

// ---------------- k_scal: scatter (u16 srcs) + alpha1 (16-wide reductions) ----
__global__ __launch_bounds__(256) void k_scal(const int* __restrict__ ei,
                                              int* __restrict__ cursor,
                                              u16* __restrict__ srcs,
                                              const u16* __restrict__ ne_b,
                                              const float* __restrict__ va_s,
                                              const float* __restrict__ va_d,
                                              float* __restrict__ as_o,
                                              float* __restrict__ ad_o) {
  int b = blockIdx.x;
  if (b < EBLK) {                                    // scatter
    int e = b * 256 + threadIdx.x;
    if (e >= ET) return;
    int s, d;
    if (e < N_EDGES) { s = ei[e]; d = ei[N_EDGES + e]; }
    else { s = d = e - N_EDGES; }
    int pos = atomicAdd(&cursor[d], 1);
    srcs[pos] = (u16)s;                              // node ids < 65536
    return;
  }
  b -= EBLK;                                         // alpha1: wave per node
  int wid = threadIdx.x >> 6, lane = threadIdx.x & 63;
  int n = b * 4 + wid;
  if (n >= N_NODES) return;
  int h = lane >> 4, il = lane & 15;                 // head, lane-in-group
  u32 u2[2];
  *(uint2*)u2 = *(const uint2*)(ne_b + (size_t)n * 64 + il * 4);
  float f[4];
  f[0] = bf2f((u16)u2[0]); f[1] = bf2f((u16)(u2[0] >> 16));
  f[2] = bf2f((u16)u2[1]); f[3] = bf2f((u16)(u2[1] >> 16));
  float4 vs = *(const float4*)(va_s + h * 64 + il * 4);
  float4 vd = *(const float4*)(va_d + h * 64 + il * 4);
  float s = f[0] * vs.x + f[1] * vs.y + f[2] * vs.z + f[3] * vs.w;
  float d = f[0] * vd.x + f[1] * vd.y + f[2] * vd.z + f[3] * vd.w;
  #pragma unroll
  for (int off = 8; off >= 1; off >>= 1) {           // 16-wide reductions
    s += __shfl_xor(s, off, 64);
    d += __shfl_xor(d, off, 64);
  }
  if (il == 0) { as_o[n * 4 + h] = s; ad_o[n * 4 + h] = d; }
}

// ---------------- layer-1 GEMM + bias + ELU + alpha2, LDS-staged epilogue ----
#define LSTR 40
#define CPAD 136   /* C-tile row stride in u16: 272B, 16B-aligned, conflict-light */
__global__ __launch_bounds__(256) void k_gemm_l1(const u16* __restrict__ aggne,
                                                 const u16* __restrict__ W1t,
                                                 const float* __restrict__ b1f,
                                                 const float* __restrict__ va2_s,
                                                 const float* __restrict__ va2_d,
                                                 u16* __restrict__ x2,
                                                 float* __restrict__ as2,
                                                 float* __restrict__ ad2, int M) {
  __shared__ __align__(16) u16 smem[128 * CPAD];   // 34.8 KB; aliases As/Bs/Cs
  u16* As = smem;                                  // 128*LSTR = 5120
  u16* Bs = smem + 128 * LSTR;                     // 5120
  const int tid = threadIdx.x;
  const int lane = tid & 63, wid = tid >> 6;
  const int wr = (wid >> 1) * 64, wc = (wid & 1) * 64;
  const int m = lane & 15, q = lane >> 4;
  const int row0 = blockIdx.x * 128, head = blockIdx.y;
  const u16* Bt = W1t + (size_t)head * 128 * 64;   // [128 rows][64]
  f32x4 acc[4][4] = {};
  #pragma unroll
  for (int kk = 0; kk < 64; kk += 32) {
    #pragma unroll
    for (int i = 0; i < 2; ++i) {             // stage A 128x32 (lda=256)
      int v = tid + i * 256;
      int row = v >> 2, ch = (v & 3) * 8;
      uint4 u = make_uint4(0, 0, 0, 0);
      int gr = row0 + row;
      if (gr < M) u = *(const uint4*)(aggne + (size_t)gr * 256 + head * 64 + kk + ch);
      *(uint4*)(As + row * LSTR + ch) = u;
    }
    #pragma unroll
    for (int i = 0; i < 2; ++i) {             // stage Bt 128x32 (stride 64)
      int v = tid + i * 256;
      int row = v >> 2, ch = (v & 3) * 8;
      uint4 u = *(const uint4*)(Bt + (size_t)row * 64 + kk + ch);
      *(uint4*)(Bs + row * LSTR + ch) = u;
    }
    __syncthreads();
    short8 af[4], bfr[4];
    #pragma unroll
    for (int t = 0; t < 4; ++t) {
      af[t]  = *(const short8*)(As + (wr + t * 16 + m) * LSTR + q * 8);
      bfr[t] = *(const short8*)(Bs + (wc + t * 16 + m) * LSTR + q * 8);
    }
    #pragma unroll
    for (int mt = 0; mt < 4; ++mt)
      #pragma unroll
      for (int nt = 0; nt < 4; ++nt)
        acc[mt][nt] = __builtin_amdgcn_mfma_f32_16x16x32_bf16(
            af[mt], bfr[nt], acc[mt][nt], 0, 0, 0);
    __syncthreads();
  }
  // bias + ELU, stage bf16 C-tile in LDS (safe: As/Bs dead after final barrier)
  u16* Cs = smem;
  #pragma unroll
  for (int mt = 0; mt < 4; ++mt) {
    #pragma unroll
    for (int nt = 0; nt < 4; ++nt) {
      int lc = wc + nt * 16 + m;              // local col in [0,128)
      float bias = b1f[head * 128 + lc];
      #pragma unroll
      for (int r = 0; r < 4; ++r) {
        float v = acc[mt][nt][r] + bias;
        v = v > 0.f ? v : (__expf(v) - 1.0f);   // ELU
        Cs[(wr + mt * 16 + q * 4 + r) * CPAD + lc] = f2bf(v);
      }
    }
  }
  __syncthreads();
  // coalesced x2 write (uint4) + alpha2 dot from staged rows
  int row = tid >> 1, half = tid & 1;         // 2 threads per row, 64 u16 each
  int gr = row0 + row;
  if (gr < M) {
    const u16* src = Cs + row * CPAD + half * 64;
    int cb = head * 128 + half * 64;
    float s = 0.f, d = 0.f;
    #pragma unroll
    for (int i = 0; i < 8; ++i) {
      uint4 u = *(const uint4*)(src + i * 8);
      *(uint4*)(x2 + (size_t)gr * 512 + cb + i * 8) = u;
      float f[8];
      unpack8(u, f);
      const float* pvs = va2_s + cb + i * 8;
      const float* pvd = va2_d + cb + i * 8;
      #pragma unroll
      for (int j = 0; j < 8; ++j) {
        s = fmaf(f[j], pvs[j], s);
        d = fmaf(f[j], pvd[j], d);
      }
    }
    s += __shfl_xor(s, 1, 64);                // partner = other half, same row
    d += __shfl_xor(d, 1, 64);
    if (half == 0) {
      atomicAdd(&as2[gr], s);
      atomicAdd(&ad2[gr], d);
    }
  }
}

// ---------------- fused layer-1 aggregation (r16/307us form, u16 srcs) ----
// NO max pass; single 16-lane-group sum-exp stats pass; gather unrolled x4.
__global__ __launch_bounds__(256) void k_fagg1(const int* __restrict__ row_off,
                                               const u16* __restrict__ srcs,
                                               const u16* __restrict__ ne_b,
                                               const float* __restrict__ as1,
                                               const float* __restrict__ ad1,
                                               u16* __restrict__ aggne) {
  int wid = threadIdx.x >> 6, lane = threadIdx.x & 63;
  int n = blockIdx.x * 4 + wid;
  if (n >= N_NODES) return;
  int start = row_off[n], end = row_off[n + 1];
  int g = lane >> 4, il = lane & 15;     // head group g, lane-in-group
  float adn_g = ad1[n * 4 + g];
  float sum = 0.f;
  for (int e0 = start; e0 < end; e0 += 16) {
    int e = e0 + il;
    if (e < end) sum += __expf(lrelu(as1[(int)srcs[e] * 4 + g] + adn_g));
  }
  #pragma unroll
  for (int off = 8; off >= 1; off >>= 1) sum += __shfl_xor(sum, off, 64);
  float inv = 1.0f / (sum + 1e-16f);
  float i_[4], d_[4];
  #pragma unroll
  for (int h = 0; h < 4; ++h) {
    i_[h] = __shfl(inv, h * 16, 64);
    d_[h] = __shfl(adn_g, h * 16, 64);
  }
  float acc[4] = {};
  for (int e0 = start; e0 < end; e0 += 64) {
    int lim = end - e0; if (lim > 64) lim = 64;
    int es = e0 + lane;
    int sreg = (int)srcs[es < end ? es : end - 1];
    float4 a = *(const float4*)(as1 + sreg * 4);
    float wreg[4];
    wreg[0] = __expf(lrelu(a.x + d_[0])) * i_[0];
    wreg[1] = __expf(lrelu(a.y + d_[1])) * i_[1];
    wreg[2] = __expf(lrelu(a.z + d_[2])) * i_[2];
    wreg[3] = __expf(lrelu(a.w + d_[3])) * i_[3];
    int j = 0;
    for (; j + 3 < lim; j += 4) {           // 4 rows in flight
      int sa = __shfl(sreg, j, 64),     sb = __shfl(sreg, j + 1, 64);
      int sc = __shfl(sreg, j + 2, 64), sd = __shfl(sreg, j + 3, 64);
      float f0 = bf2f(ne_b[(size_t)sa * 64 + lane]);
      float f1 = bf2f(ne_b[(size_t)sb * 64 + lane]);
      float f2 = bf2f(ne_b[(size_t)sc * 64 + lane]);
      float f3 = bf2f(ne_b[(size_t)sd * 64 + lane]);
      #pragma unroll
      for (int h = 0; h < 4; ++h) {
        acc[h] = fmaf(__shfl(wreg[h], j, 64), f0, acc[h]);
        acc[h] = fmaf(__shfl(wreg[h], j + 1, 64), f1, acc[h]);
        acc[h] = fmaf(__shfl(wreg[h], j + 2, 64), f2, acc[h]);
        acc[h] = fmaf(__shfl(wreg[h], j + 3, 64), f3, acc[h]);
      }
    }
    for (; j < lim; ++j) {
      int sa = __shfl(sreg, j, 64);
      float f0 = bf2f(ne_b[(size_t)sa * 64 + lane]);
      #pragma unroll
      for (int h = 0; h < 4; ++h)
        acc[h] = fmaf(__shfl(wreg[h], j, 64), f0, acc[h]);
    }
  }
  #pragma unroll
  for (int h = 0; h < 4; ++h)
    aggne[(size_t)n * 256 + h * 64 + lane] = f2bf(acc[h]);
}

// ---------------- layer-2: per-src total softmax weight c[s], no max pass ----
__global__ __launch_bounds__(256) void k_nodew(const int* __restrict__ row_off,
                                               const u16* __restrict__ srcs,
                                               const float* __restrict__ as2,
                                               const float* __restrict__ ad2,
                                               float* __restrict__ c) {
  int wid = threadIdx.x >> 6, lane = threadIdx.x & 63;
  int n = blockIdx.x * 4 + wid;
  if (n >= N_NODES) return;
  int start = row_off[n], end = row_off[n + 1];
  int deg = end - start;
  float adn = ad2[n];
  if (deg <= 64) {
    int e = start + (lane < deg ? lane : 0);
    int s = (int)srcs[e];
    float ex = (lane < deg) ? __expf(lrelu(as2[s] + adn)) : 0.f;
    float sum = ex;
    #pragma unroll
    for (int off = 32; off >= 1; off >>= 1) sum += __shfl_xor(sum, off, 64);
    float w = ex / (sum + 1e-16f);
    if (lane < deg) atomicAdd(&c[s], w);
  } else {
    float sum = 0.f;
    for (int e = start + lane; e < end; e += 64)
      sum += __expf(lrelu(as2[(int)srcs[e]] + adn));
    #pragma unroll
    for (int off = 32; off >= 1; off >>= 1) sum += __shfl_xor(sum, off, 64);
    float inv = 1.0f / (sum + 1e-16f);
    for (int e = start + lane; e < end; e += 64) {
      int s = (int)srcs[e];
      float w = __expf(lrelu(as2[s] + adn)) * inv;
      atomicAdd(&c[s], w);
    }
  }
}

// ---------------- weighted column sum: s_vec[ch] = sum_n c[n]*x2[n][ch] ----
__global__ __launch_bounds__(256) void k_wsum(const u16* __restrict__ x2,
                                              const float* __restrict__ c,
                                              float* __restrict__ s_vec) {
  __shared__ float part[4][512];
  int wid = threadIdx.x >> 6, lane = threadIdx.x & 63;
  int wglob = blockIdx.x * 4 + wid;
  float acc[8] = {};
  int n = wglob;
  for (; n + WSB * 4 < N_NODES; n += WSB * 8) {   // two rows in flight
    int n2 = n + WSB * 4;
    float c0 = c[n], c1 = c[n2];
    uint4 u0 = *(const uint4*)(x2 + (size_t)n * 512 + lane * 8);
    uint4 u1 = *(const uint4*)(x2 + (size_t)n2 * 512 + lane * 8);
    float f0[8], f1[8];
    unpack8(u0, f0); unpack8(u1, f1);
    #pragma unroll
    for (int j = 0; j < 8; ++j) {
      acc[j] = fmaf(c0, f0[j], acc[j]);
      acc[j] = fmaf(c1, f1[j], acc[j]);
    }
  }
  if (n < N_NODES) {
    float c0 = c[n];
    uint4 u0 = *(const uint4*)(x2 + (size_t)n * 512 + lane * 8);
    float f0[8];
    unpack8(u0, f0);
    #pragma unroll
    for (int j = 0; j < 8; ++j) acc[j] = fmaf(c0, f0[j], acc[j]);
  }
  #pragma unroll
  for (int j = 0; j < 8; ++j) part[wid][lane * 8 + j] = acc[j];
  __syncthreads();
  int t = threadIdx.x;
  float v0 = part[0][t] + part[1][t] + part[2][t] + part[3][t];
  float v1 = part[0][t + 256] + part[1][t + 256] + part[2][t + 256] + part[3][t + 256];
  atomicAdd(&s_vec[t], v0);
  atomicAdd(&s_vec[t + 256], v1);
}

// ---------------- tiny GEMM + final output (merged) ----------------
__global__ __launch_bounds__(256) void k_tinyfinal(const float* __restrict__ s_vec,
                                                   const u16* __restrict__ W2t,
                                                   const float* __restrict__ b2f,
                                                   float* __restrict__ out,
                                                   int out_size) {
  int wid = threadIdx.x >> 6, lane = threadIdx.x & 63;
  int cbase = blockIdx.x * 64 + wid * 16;
  float sv[8];
  #pragma unroll
  for (int j = 0; j < 8; ++j) sv[j] = s_vec[lane * 8 + j];
  for (int i = 0; i < 16; ++i) {
    int cc = cbase + i;
    uint4 u = *(const uint4*)(W2t + (size_t)cc * 512 + lane * 8);
    float f[8];
    unpack8(u, f);
    float p = 0.f;
    #pragma unroll
    for (int j = 0; j < 8; ++j) p = fmaf(sv[j], f[j], p);
    #pragma unroll
    for (int off = 32; off >= 1; off >>= 1) p += __shfl_xor(p, off, 64);
    if (lane == 0) {
      float val = p * (1.0f / (float)N_NODES) + b2f[cc];
      for (int o = cc; o < out_size; o += 256) out[o] = val;
    }
  }
}

// ---------------- launch ----------------
extern "C" void kernel_launch(void* const* d_in, const int* in_sizes, int n_in,
                              void* d_out, int out_size, void* d_ws, size_t ws_size,
                              hipStream_t stream) {
  (void)in_sizes; (void)n_in; (void)ws_size;
  const int* edge_index = (const int*)d_in[0];
  float* out = (float*)d_out;   // reference output dtype is float32

  char* w = (char*)d_ws;
  size_t off = 0;
  auto alloc = [&](size_t bytes) -> void* {
    void* p = w + off;
    off += (bytes + 255) & ~(size_t)255;
    return p;
  };
  u16*   ne_b    = (u16*)  alloc((size_t)N_NODES * 64 * 2);   // 6.4 MB bf16
  u16*   W1t     = (u16*)  alloc(32768 * 2);                  // [512][64]
  u16*   W2t     = (u16*)  alloc(131072 * 2);                 // [256][512]
  float* as1v    = (float*)alloc(512 * 4);
  float* ad1v    = (float*)alloc(512 * 4);
  float* b1f     = (float*)alloc(512 * 4);
  float* as2v    = (float*)alloc(256 * 4);
  float* ad2v    = (float*)alloc(256 * 4);
  float* b2f     = (float*)alloc(256 * 4);
  float* va_s    = (float*)alloc(256 * 4);
  float* va_d    = (float*)alloc(256 * 4);
  float* va2_s   = (float*)alloc(512 * 4);
  float* va2_d   = (float*)alloc(512 * 4);
  u16*   aggne   = (u16*)  alloc((size_t)N_NODES * 256 * 2);  // 25.6 MB
  u16*   x2      = (u16*)  alloc((size_t)N_NODES * 512 * 2);  // 51.2 MB
  float* as1     = (float*)alloc((size_t)N_NODES * 4 * 4);
  float* ad1     = (float*)alloc((size_t)N_NODES * 4 * 4);
  // ---- zeroed-every-call region (contiguous, one memset) ----
  size_t z0 = off;
  float* as2     = (float*)alloc((size_t)N_NODES * 4);
  float* ad2     = (float*)alloc((size_t)N_NODES * 4);
  float* cwt     = (float*)alloc((size_t)N_NODES * 4);
  float* s_vec   = (float*)alloc(512 * 4);
  int*   deg     = (int*)  alloc((size_t)N_NODES * 4);
  size_t z1 = off;
  // -----------------------------------------------------------
  int*   row_off = (int*)  alloc((size_t)(N_NODES + 1) * 4);
  int*   cursor  = (int*)  alloc((size_t)N_NODES * 4);
  u16*   srcs    = (u16*)  alloc((size_t)ET * 2);             // node ids fit u16
  int*   btot    = (int*)  alloc(64 * 4);
  int*   bbase   = (int*)  alloc(64 * 4);

  hipMemsetAsync(w + z0, 0, z1 - z0, stream);

  // prep: degree + ne cvt + weight transposes + params (inline dtype detect)
  k_prep<<<EBLK + NEBLK + 640 + 9, 256, 0, stream>>>(
      edge_index, deg, d_in[2], ne_b, d_in[3], W1t, d_in[7], W2t,
      d_in[4], d_in[5], d_in[6], d_in[8], d_in[9], d_in[10],
      as1v, ad1v, b1f, as2v, ad2v, b2f);
  k_vab<<<3, 256, 0, stream>>>(W1t, as1v, ad1v, va_s, va_d,
                               W2t, as2v, ad2v, va2_s, va2_d);

  // CSR scan
  k_partial<<<49, 1024, 0, stream>>>(deg, row_off, btot);
  k_bases  <<<1, 64, 0, stream>>>(btot, bbase, row_off, 49);
  k_add    <<<49, 1024, 0, stream>>>(row_off, cursor, bbase);

  // scatter (u16 srcs) + alpha1 (merged, 16-wide reductions)
  k_scal<<<EBLK + (N_NODES + 3) / 4, 256, 0, stream>>>(
      edge_index, cursor, srcs, ne_b, va_s, va_d, as1, ad1);

  // layer 1: fused agg over ne (r16 form), GEMM(+bias+ELU+alpha2) -> x2
  k_fagg1<<<(N_NODES + 3) / 4, 256, 0, stream>>>(row_off, srcs, ne_b, as1, ad1, aggne);
  dim3 gl1((N_NODES + 127) / 128, 4);
  k_gemm_l1<<<gl1, 256, 0, stream>>>(aggne, W1t, b1f, va2_s, va2_d, x2, as2, ad2,
                                     N_NODES);

  // layer 2 (mean-reassociated)
  k_nodew<<<(N_NODES + 3) / 4, 256, 0, stream>>>(row_off, srcs, as2, ad2, cwt);
  k_wsum<<<WSB, 256, 0, stream>>>(x2, cwt, s_vec);
  k_tinyfinal<<<4, 256, 0, stream>>>(s_vec, W2t, b2f, out, out_size);
}